// Round 1
// baseline (739.930 us; speedup 1.0000x reference)
//
#include <hip/hip_runtime.h>
#include <math.h>

#define N_NODES 50000
#define E_EDGES 800000
#define FIN     128
#define HC1     256   // H*C = 4*64
#define C2      64
#define NGRAPH  8

// ---------------------------------------------------------------- GEMM (f32)
// C[N,M] = A[N,K] @ B[K,M], row-major. 64x64 tile, 256 threads, 4x4 microtile.
__global__ __launch_bounds__(256) void gemm_f32(
    const float* __restrict__ A, const float* __restrict__ B,
    float* __restrict__ C, int N, int K, int M) {
  __shared__ float As[16][68];  // [k][row], padded to 68 for aligned float4
  __shared__ float Bs[16][64];  // [k][col]
  const int tid  = threadIdx.x;
  const int row0 = blockIdx.x * 64;
  const int col0 = blockIdx.y * 64;
  const int tr = (tid >> 4) * 4;
  const int tc = (tid & 15) * 4;
  const int ar = tid >> 2;           // 0..63
  const int ak = (tid & 3) * 4;      // 0,4,8,12
  const int bk = tid >> 4;           // 0..15
  const int bc = (tid & 15) * 4;     // 0..60
  float acc[4][4] = {};
  for (int k0 = 0; k0 < K; k0 += 16) {
    float4 av = make_float4(0.f, 0.f, 0.f, 0.f);
    const int arow = row0 + ar;
    if (arow < N) av = *(const float4*)(A + (size_t)arow * K + k0 + ak);
    As[ak + 0][ar] = av.x; As[ak + 1][ar] = av.y;
    As[ak + 2][ar] = av.z; As[ak + 3][ar] = av.w;
    *(float4*)&Bs[bk][bc] = *(const float4*)(B + (size_t)(k0 + bk) * M + col0 + bc);
    __syncthreads();
#pragma unroll
    for (int kk = 0; kk < 16; kk++) {
      const float4 a = *(const float4*)&As[kk][tr];
      const float4 b = *(const float4*)&Bs[kk][tc];
      acc[0][0] += a.x * b.x; acc[0][1] += a.x * b.y; acc[0][2] += a.x * b.z; acc[0][3] += a.x * b.w;
      acc[1][0] += a.y * b.x; acc[1][1] += a.y * b.y; acc[1][2] += a.y * b.z; acc[1][3] += a.y * b.w;
      acc[2][0] += a.z * b.x; acc[2][1] += a.z * b.y; acc[2][2] += a.z * b.z; acc[2][3] += a.z * b.w;
      acc[3][0] += a.w * b.x; acc[3][1] += a.w * b.y; acc[3][2] += a.w * b.z; acc[3][3] += a.w * b.w;
    }
    __syncthreads();
  }
#pragma unroll
  for (int i = 0; i < 4; i++) {
    const int row = row0 + tr + i;
    if (row < N) {
      float4 o = make_float4(acc[i][0], acc[i][1], acc[i][2], acc[i][3]);
      *(float4*)(C + (size_t)row * M + col0 + tc) = o;
    }
  }
}

// ------------------------------------------------------------- CSR building
__global__ void count_deg(const int* __restrict__ dst, int E, int* __restrict__ deg) {
  const int e = blockIdx.x * 256 + threadIdx.x;
  if (e < E) atomicAdd(&deg[dst[e]], 1);
}

__global__ __launch_bounds__(1024) void scan_kernel(
    const int* __restrict__ deg, int* __restrict__ offs, int* __restrict__ cursor, int N) {
  __shared__ int sdata[1024];
  __shared__ int carry;
  const int tid = threadIdx.x;
  if (tid == 0) { carry = 0; offs[0] = 0; }
  __syncthreads();
  for (int base = 0; base < N; base += 1024) {
    const int i = base + tid;
    const int v = (i < N) ? deg[i] : 0;
    sdata[tid] = v;
    __syncthreads();
    for (int off = 1; off < 1024; off <<= 1) {
      int t = 0;
      if (tid >= off) t = sdata[tid - off];
      __syncthreads();
      if (tid >= off) sdata[tid] += t;
      __syncthreads();
    }
    const int inc = sdata[tid] + carry;  // inclusive scan + carry
    if (i < N) { offs[i + 1] = inc; cursor[i] = inc - v; }
    __syncthreads();
    if (tid == 1023) carry = inc;
    __syncthreads();
  }
}

__global__ void scatter_kernel(const int* __restrict__ src, const int* __restrict__ dst,
                               int E, int* __restrict__ cursor, int* __restrict__ esrc) {
  const int e = blockIdx.x * 256 + threadIdx.x;
  if (e < E) {
    const int pos = atomicAdd(&cursor[dst[e]], 1);
    esrc[pos] = src[e];
  }
}

// --------------------------------------------- fused gather+softmax+aggregate
// Layer 1: H=4 heads x C=64 ch. One wave per dst node; lane owns channels
// 4*lane..4*lane+3 (head = lane>>4). Online softmax in registers.
__global__ __launch_bounds__(256) void agg1_kernel(
    const float* __restrict__ xl, const float* __restrict__ xr,
    const float* __restrict__ att, const float* __restrict__ bias,
    const int* __restrict__ offs, const int* __restrict__ esrc,
    float* __restrict__ out, int N) {
  const int lane = threadIdx.x & 63;
  const int d = blockIdx.x * 4 + (threadIdx.x >> 6);
  if (d >= N) return;
  const float4 xr4 = *(const float4*)(xr + (size_t)d * HC1 + lane * 4);
  const float4 at4 = *(const float4*)(att + lane * 4);  // att[h][c], h=lane>>4
  const int beg = offs[d], end = offs[d + 1];
  float m = -INFINITY, l = 0.f;
  float ax = 0.f, ay = 0.f, az = 0.f, aw = 0.f;
  for (int i = beg; i <= end; i++) {     // i==end -> self loop
    const int s = (i < end) ? esrc[i] : d;
    const float4 xl4 = *(const float4*)(xl + (size_t)s * HC1 + lane * 4);
    float ex = xl4.x + xr4.x; ex = ex > 0.f ? ex : 0.2f * ex;
    float ey = xl4.y + xr4.y; ey = ey > 0.f ? ey : 0.2f * ey;
    float ez = xl4.z + xr4.z; ez = ez > 0.f ? ez : 0.2f * ez;
    float ew = xl4.w + xr4.w; ew = ew > 0.f ? ew : 0.2f * ew;
    float p = ex * at4.x + ey * at4.y + ez * at4.z + ew * at4.w;
    p += __shfl_xor(p, 1);
    p += __shfl_xor(p, 2);
    p += __shfl_xor(p, 4);
    p += __shfl_xor(p, 8);               // per-head score (16-lane groups)
    const float mn = fmaxf(m, p);
    const float sc = expf(m - mn);       // m=-inf first iter -> 0
    const float w  = expf(p - mn);
    l  = l  * sc + w;
    ax = ax * sc + w * xl4.x;
    ay = ay * sc + w * xl4.y;
    az = az * sc + w * xl4.z;
    aw = aw * sc + w * xl4.w;
    m = mn;
  }
  const float inv = 1.f / (l + 1e-16f);
  const float4 b4 = *(const float4*)(bias + lane * 4);
  float4 o;
  o.x = fmaxf(ax * inv + b4.x, 0.f);     // + b1, then ReLU
  o.y = fmaxf(ay * inv + b4.y, 0.f);
  o.z = fmaxf(az * inv + b4.z, 0.f);
  o.w = fmaxf(aw * inv + b4.w, 0.f);
  *(float4*)(out + (size_t)d * HC1 + lane * 4) = o;
}

// Layer 2: 1 head x 64 ch. One wave per dst node; lane owns channel `lane`.
__global__ __launch_bounds__(256) void agg2_kernel(
    const float* __restrict__ xl, const float* __restrict__ xr,
    const float* __restrict__ att, const float* __restrict__ bias,
    const int* __restrict__ offs, const int* __restrict__ esrc,
    float* __restrict__ out, int N) {
  const int lane = threadIdx.x & 63;
  const int d = blockIdx.x * 4 + (threadIdx.x >> 6);
  if (d >= N) return;
  const float xrv = xr[(size_t)d * C2 + lane];
  const float atv = att[lane];
  const int beg = offs[d], end = offs[d + 1];
  float m = -INFINITY, l = 0.f, acc = 0.f;
  for (int i = beg; i <= end; i++) {
    const int s = (i < end) ? esrc[i] : d;
    const float xlv = xl[(size_t)s * C2 + lane];
    float e = xlv + xrv; e = e > 0.f ? e : 0.2f * e;
    float p = e * atv;
    p += __shfl_xor(p, 1);
    p += __shfl_xor(p, 2);
    p += __shfl_xor(p, 4);
    p += __shfl_xor(p, 8);
    p += __shfl_xor(p, 16);
    p += __shfl_xor(p, 32);              // full-wave score
    const float mn = fmaxf(m, p);
    const float sc = expf(m - mn);
    const float w  = expf(p - mn);
    l   = l   * sc + w;
    acc = acc * sc + w * xlv;
    m = mn;
  }
  out[(size_t)d * C2 + lane] = acc / (l + 1e-16f) + bias[lane];
}

// ------------------------------------------------------------------- pooling
// batch is sorted; wave handles a contiguous node range, lane = channel,
// register-accumulate per graph, atomic flush on graph change.
__global__ __launch_bounds__(256) void pool_kernel(
    const float* __restrict__ h, const int* __restrict__ batch, int N,
    float* __restrict__ pooled, float* __restrict__ cnt) {
  const int wid  = (blockIdx.x * blockDim.x + threadIdx.x) >> 6;
  const int lane = threadIdx.x & 63;
  const int nw   = (gridDim.x * blockDim.x) >> 6;
  const int per  = (N + nw - 1) / nw;
  const int beg  = wid * per;
  if (beg >= N) return;
  const int end = min(beg + per, N);
  int g = batch[beg];
  float acc = 0.f, c = 0.f;
  for (int d = beg; d < end; d++) {
    const int gd = batch[d];
    if (gd != g) {
      atomicAdd(&pooled[g * C2 + lane], acc);
      if (lane == 0) atomicAdd(&cnt[g], c);
      acc = 0.f; c = 0.f; g = gd;
    }
    acc += h[(size_t)d * C2 + lane];
    c += 1.f;
  }
  atomicAdd(&pooled[g * C2 + lane], acc);
  if (lane == 0) atomicAdd(&cnt[g], c);
}

__global__ void final_kernel(const float* __restrict__ pooled, const float* __restrict__ cnt,
                             const float* __restrict__ Wo, const float* __restrict__ bo,
                             float* __restrict__ out) {
  const int lane = threadIdx.x;  // 64 threads
  for (int g = 0; g < NGRAPH; g++) {
    float p = (pooled[g * C2 + lane] / fmaxf(cnt[g], 1.f)) * Wo[lane];
    p += __shfl_xor(p, 1);
    p += __shfl_xor(p, 2);
    p += __shfl_xor(p, 4);
    p += __shfl_xor(p, 8);
    p += __shfl_xor(p, 16);
    p += __shfl_xor(p, 32);
    if (lane == 0) out[g] = p + bo[0];
  }
}

// ---------------------------------------------------------------------------
extern "C" void kernel_launch(void* const* d_in, const int* in_sizes, int n_in,
                              void* d_out, int out_size, void* d_ws, size_t ws_size,
                              hipStream_t stream) {
  const float* x    = (const float*)d_in[0];
  const int*   edge = (const int*)d_in[1];     // [2,E]: row0=src, row1=dst
  const int*   batch= (const int*)d_in[2];
  const float* Wl1  = (const float*)d_in[3];
  const float* Wr1  = (const float*)d_in[4];
  const float* att1 = (const float*)d_in[5];
  const float* b1   = (const float*)d_in[6];
  const float* Wl2  = (const float*)d_in[7];
  const float* Wr2  = (const float*)d_in[8];
  const float* att2 = (const float*)d_in[9];
  const float* b2   = (const float*)d_in[10];
  const float* Wo   = (const float*)d_in[11];
  const float* bo   = (const float*)d_in[12];
  float* out = (float*)d_out;

  char* p = (char*)d_ws;
  const size_t SZ1 = (size_t)N_NODES * HC1 * 4;  // 51.2 MB
  const size_t SZ2 = (size_t)N_NODES * C2 * 4;   // 12.8 MB
  float* xl1 = (float*)p;
  float* xr1 = (float*)(p + SZ1);
  float* h1  = (float*)(p + 2 * SZ1);
  // reuse region of xl1/xr1 after layer-1 aggregation:
  float* xl2  = (float*)p;
  float* xr2  = (float*)(p + SZ2);
  float* out2 = (float*)(p + 2 * SZ2);
  char* aux = p + 3 * SZ1;
  int* deg    = (int*)aux;                                  // N ints
  int* offs   = (int*)(aux + 200000);                       // N+1 ints
  int* cursor = (int*)(aux + 200000 + 200064);              // N ints
  int* esrc   = (int*)(aux + 200000 + 200064 + 200000);     // E ints
  float* pooled = (float*)(aux + 200000 + 200064 + 200000 + 3200000);  // 8*64
  float* cnt    = pooled + NGRAPH * C2;                     // 8

  const int* edst = edge + E_EDGES;

  hipMemsetAsync(deg, 0, (size_t)N_NODES * 4, stream);
  hipMemsetAsync(pooled, 0, (NGRAPH * C2 + NGRAPH) * 4, stream);

  // layer-1 node transforms
  dim3 gA((N_NODES + 63) / 64, HC1 / 64);
  gemm_f32<<<gA, 256, 0, stream>>>(x, Wl1, xl1, N_NODES, FIN, HC1);
  gemm_f32<<<gA, 256, 0, stream>>>(x, Wr1, xr1, N_NODES, FIN, HC1);

  // CSR by dst (self-loops handled implicitly in agg kernels)
  count_deg<<<(E_EDGES + 255) / 256, 256, 0, stream>>>(edst, E_EDGES, deg);
  scan_kernel<<<1, 1024, 0, stream>>>(deg, offs, cursor, N_NODES);
  scatter_kernel<<<(E_EDGES + 255) / 256, 256, 0, stream>>>(edge, edst, E_EDGES, cursor, esrc);

  // layer 1 attention + aggregate (+b1, ReLU)
  agg1_kernel<<<(N_NODES + 3) / 4, 256, 0, stream>>>(xl1, xr1, att1, b1, offs, esrc, h1, N_NODES);

  // layer-2 node transforms
  dim3 gB((N_NODES + 63) / 64, C2 / 64);
  gemm_f32<<<gB, 256, 0, stream>>>(h1, Wl2, xl2, N_NODES, HC1, C2);
  gemm_f32<<<gB, 256, 0, stream>>>(h1, Wr2, xr2, N_NODES, HC1, C2);

  // layer 2 attention + aggregate (+b2)
  agg2_kernel<<<(N_NODES + 3) / 4, 256, 0, stream>>>(xl2, xr2, att2, b2, offs, esrc, out2, N_NODES);

  // mean pool per graph, then @ Wo + bo
  pool_kernel<<<196, 256, 0, stream>>>(out2, batch, N_NODES, pooled, cnt);
  final_kernel<<<1, 64, 0, stream>>>(pooled, cnt, Wo, bo, out);
}

// Round 2
// 571.850 us; speedup vs baseline: 1.2939x; 1.2939x over previous
//
#include <hip/hip_runtime.h>
#include <math.h>

#define N_NODES 50000
#define E_EDGES 800000
#define FIN     128
#define HC1     256   // H*C = 4*64
#define C2      64
#define NGRAPH  8
#define LOG2E   1.4426950408889634f

typedef short s16x8 __attribute__((ext_vector_type(8)));
typedef float f32x4 __attribute__((ext_vector_type(4)));

__device__ __forceinline__ unsigned short f2bf(float f) {
  union { float f; unsigned u; } v; v.f = f;
  unsigned r = v.u + 0x7FFFu + ((v.u >> 16) & 1u);  // RNE
  return (unsigned short)(r >> 16);
}
__device__ __forceinline__ float bf2f(unsigned short s) {
  union { unsigned u; float f; } v; v.u = ((unsigned)s) << 16;
  return v.f;
}

// ----------------------------------------------------- weight transpose+cast
// Bt[n][k] (bf16) from cat(B0,B1) where B0/B1 are [K][M1] f32. K = 1<<kshift.
__global__ void transpose_cat(const float* __restrict__ B0, const float* __restrict__ B1,
                              int M1, int kshift, unsigned short* __restrict__ Bt, int total) {
  const int idx = blockIdx.x * 256 + threadIdx.x;
  if (idx >= total) return;
  const int K = 1 << kshift;
  const int n = idx >> kshift, k = idx & (K - 1);
  const float* B = (n < M1) ? B0 : B1;
  const int nn = (n < M1) ? n : n - M1;
  Bt[idx] = f2bf(B[(size_t)k * M1 + nn]);
}

// --------------------------------------------------------- MFMA bf16 GEMM
// C[N x Mtot] bf16 = A[N x KTOT] @ Bt^T, Bt is [Mtot][KTOT] bf16 (pre-transposed).
// Block: 256 thr = 4 waves, tile 128x128, K-chunk 64. Wave computes 64x64
// via 16 x mfma_f32_16x16x32_bf16 tiles. AISBF: A already bf16 (else f32).
template<int KTOT, int AISBF>
__global__ __launch_bounds__(256) void gemm_mfma(
    const void* __restrict__ Av, const unsigned short* __restrict__ Bt,
    unsigned short* __restrict__ Cc, int N, int Mtot) {
  __shared__ short Asm[128 * 72];  // [row][k], pitch 72 shorts (16B-aligned rows)
  __shared__ short Bsm[128 * 72];  // [col][k]
  const int tid  = threadIdx.x;
  const int lane = tid & 63;
  const int wave = tid >> 6;
  const int lm   = lane & 15, quad = lane >> 4;
  const int r0   = blockIdx.x * 128;
  const int c0   = blockIdx.y * 128;
  const int wrow = (wave & 1) * 64;
  const int wcol = (wave >> 1) * 64;
  const int srow = tid >> 1;          // 0..127 staging row
  const int scol = (tid & 1) * 32;    // staging k-half

  f32x4 acc[4][4];
#pragma unroll
  for (int mt = 0; mt < 4; mt++)
#pragma unroll
    for (int nt = 0; nt < 4; nt++)
      acc[mt][nt] = (f32x4){0.f, 0.f, 0.f, 0.f};

  const int arow = min(r0 + srow, N - 1);
  for (int kc = 0; kc < KTOT; kc += 64) {
    if (AISBF) {
      const unsigned short* A = (const unsigned short*)Av;
#pragma unroll
      for (int i = 0; i < 4; i++) {
        const int col = scol + i * 8;
        *(uint4*)&Asm[srow * 72 + col] = *(const uint4*)&A[(size_t)arow * KTOT + kc + col];
      }
    } else {
      const float* A = (const float*)Av;
#pragma unroll
      for (int i = 0; i < 4; i++) {
        const int col = scol + i * 8;
        const float4 v0 = *(const float4*)&A[(size_t)arow * KTOT + kc + col];
        const float4 v1 = *(const float4*)&A[(size_t)arow * KTOT + kc + col + 4];
        ushort4 u0 = { f2bf(v0.x), f2bf(v0.y), f2bf(v0.z), f2bf(v0.w) };
        ushort4 u1 = { f2bf(v1.x), f2bf(v1.y), f2bf(v1.z), f2bf(v1.w) };
        *(ushort4*)&Asm[srow * 72 + col]     = u0;
        *(ushort4*)&Asm[srow * 72 + col + 4] = u1;
      }
    }
#pragma unroll
    for (int i = 0; i < 4; i++) {
      const int col = scol + i * 8;
      *(uint4*)&Bsm[srow * 72 + col] = *(const uint4*)&Bt[(size_t)(c0 + srow) * KTOT + kc + col];
    }
    __syncthreads();
#pragma unroll
    for (int s = 0; s < 2; s++) {
      s16x8 af[4], bfr[4];
#pragma unroll
      for (int mt = 0; mt < 4; mt++)
        af[mt] = *(const s16x8*)&Asm[(wrow + mt * 16 + lm) * 72 + s * 32 + quad * 8];
#pragma unroll
      for (int nt = 0; nt < 4; nt++)
        bfr[nt] = *(const s16x8*)&Bsm[(wcol + nt * 16 + lm) * 72 + s * 32 + quad * 8];
#pragma unroll
      for (int mt = 0; mt < 4; mt++)
#pragma unroll
        for (int nt = 0; nt < 4; nt++)
          acc[mt][nt] = __builtin_amdgcn_mfma_f32_16x16x32_bf16(af[mt], bfr[nt], acc[mt][nt], 0, 0, 0);
    }
    __syncthreads();
  }
#pragma unroll
  for (int mt = 0; mt < 4; mt++) {
#pragma unroll
    for (int r = 0; r < 4; r++) {
      const int row = r0 + wrow + mt * 16 + quad * 4 + r;
      if (row < N) {
#pragma unroll
        for (int nt = 0; nt < 4; nt++) {
          const int col = c0 + wcol + nt * 16 + lm;
          Cc[(size_t)row * Mtot + col] = f2bf(acc[mt][nt][r]);
        }
      }
    }
  }
}

// ------------------------------------------------------------- CSR building
__global__ void count_deg(const int* __restrict__ dst, int E, int* __restrict__ deg) {
  const int e = blockIdx.x * 256 + threadIdx.x;
  if (e < E) atomicAdd(&deg[dst[e]], 1);
}

__global__ __launch_bounds__(1024) void scan_kernel(
    const int* __restrict__ deg, int* __restrict__ offs, int* __restrict__ cursor, int N) {
  __shared__ int sdata[1024];
  __shared__ int carry;
  const int tid = threadIdx.x;
  if (tid == 0) { carry = 0; offs[0] = 0; }
  __syncthreads();
  for (int base = 0; base < N; base += 1024) {
    const int i = base + tid;
    const int v = (i < N) ? deg[i] : 0;
    sdata[tid] = v;
    __syncthreads();
    for (int off = 1; off < 1024; off <<= 1) {
      int t = 0;
      if (tid >= off) t = sdata[tid - off];
      __syncthreads();
      if (tid >= off) sdata[tid] += t;
      __syncthreads();
    }
    const int inc = sdata[tid] + carry;
    if (i < N) { offs[i + 1] = inc; cursor[i] = inc - v; }
    __syncthreads();
    if (tid == 1023) carry = inc;
    __syncthreads();
  }
}

__global__ void scatter_kernel(const int* __restrict__ src, const int* __restrict__ dst,
                               int E, int* __restrict__ cursor, int* __restrict__ esrc) {
  const int e = blockIdx.x * 256 + threadIdx.x;
  if (e < E) {
    const int pos = atomicAdd(&cursor[dst[e]], 1);
    esrc[pos] = src[e];
  }
}

// --------------------------------------------- fused gather+softmax+aggregate
// Layer 1: xlr[n][512] bf16 (cols 0:256 xl, 256:512 xr). Wave per dst node;
// lane owns 4 channels. Plain exp softmax (scores bounded ~|p|<3).
__global__ __launch_bounds__(256) void agg1_kernel(
    const unsigned short* __restrict__ xlr, const float* __restrict__ att,
    const float* __restrict__ bias, const int* __restrict__ offs,
    const int* __restrict__ esrc, unsigned short* __restrict__ out, int N) {
  const int lane = threadIdx.x & 63;
  const int d = blockIdx.x * 4 + (threadIdx.x >> 6);
  if (d >= N) return;
  const ushort4 xru = *(const ushort4*)(xlr + (size_t)d * 512 + 256 + lane * 4);
  const float xr0 = bf2f(xru.x), xr1 = bf2f(xru.y), xr2 = bf2f(xru.z), xr3 = bf2f(xru.w);
  const float4 at4 = *(const float4*)(att + lane * 4);   // att[h][c], h=lane>>4
  const float a0 = at4.x * LOG2E, a1 = at4.y * LOG2E, a2 = at4.z * LOG2E, a3 = at4.w * LOG2E;
  const int beg = offs[d], end = offs[d + 1];
  float l = 0.f, ax = 0.f, ay = 0.f, az = 0.f, aw = 0.f;
  for (int i = beg; i <= end; i++) {      // i==end -> self loop
    const int s = (i < end) ? esrc[i] : d;
    const ushort4 xu = *(const ushort4*)(xlr + (size_t)s * 512 + lane * 4);
    const float x0 = bf2f(xu.x), x1 = bf2f(xu.y), x2 = bf2f(xu.z), x3 = bf2f(xu.w);
    float e0 = x0 + xr0; e0 = e0 > 0.f ? e0 : 0.2f * e0;
    float e1 = x1 + xr1; e1 = e1 > 0.f ? e1 : 0.2f * e1;
    float e2 = x2 + xr2; e2 = e2 > 0.f ? e2 : 0.2f * e2;
    float e3 = x3 + xr3; e3 = e3 > 0.f ? e3 : 0.2f * e3;
    float p = e0 * a0 + e1 * a1 + e2 * a2 + e3 * a3;
    p += __shfl_xor(p, 1);
    p += __shfl_xor(p, 2);
    p += __shfl_xor(p, 4);
    p += __shfl_xor(p, 8);                // per-head score (16-lane groups)
    const float w = exp2f(p);             // log2e folded into att
    l += w; ax += w * x0; ay += w * x1; az += w * x2; aw += w * x3;
  }
  const float inv = 1.f / (l + 1e-16f);
  const float4 b4 = *(const float4*)(bias + lane * 4);
  ushort4 o;
  o.x = f2bf(fmaxf(ax * inv + b4.x, 0.f));   // +b1, ReLU
  o.y = f2bf(fmaxf(ay * inv + b4.y, 0.f));
  o.z = f2bf(fmaxf(az * inv + b4.z, 0.f));
  o.w = f2bf(fmaxf(aw * inv + b4.w, 0.f));
  *(ushort4*)(out + (size_t)d * 256 + lane * 4) = o;
}

// Layer 2: xlr[n][128] bf16 (cols 0:64 xl, 64:128 xr). Lane owns 1 channel.
__global__ __launch_bounds__(256) void agg2_kernel(
    const unsigned short* __restrict__ xlr, const float* __restrict__ att,
    const float* __restrict__ bias, const int* __restrict__ offs,
    const int* __restrict__ esrc, float* __restrict__ out, int N) {
  const int lane = threadIdx.x & 63;
  const int d = blockIdx.x * 4 + (threadIdx.x >> 6);
  if (d >= N) return;
  const float xr = bf2f(xlr[(size_t)d * 128 + 64 + lane]);
  const float atv = att[lane] * LOG2E;
  const int beg = offs[d], end = offs[d + 1];
  float l = 0.f, acc = 0.f;
  for (int i = beg; i <= end; i++) {
    const int s = (i < end) ? esrc[i] : d;
    const float xl = bf2f(xlr[(size_t)s * 128 + lane]);
    float e = xl + xr; e = e > 0.f ? e : 0.2f * e;
    float p = e * atv;
    p += __shfl_xor(p, 1);
    p += __shfl_xor(p, 2);
    p += __shfl_xor(p, 4);
    p += __shfl_xor(p, 8);
    p += __shfl_xor(p, 16);
    p += __shfl_xor(p, 32);
    const float w = exp2f(p);
    l += w; acc += w * xl;
  }
  out[(size_t)d * 64 + lane] = acc / (l + 1e-16f) + bias[lane];
}

// ------------------------------------------------------------------- pooling
__global__ __launch_bounds__(256) void pool_kernel(
    const float* __restrict__ h, const int* __restrict__ batch, int N,
    float* __restrict__ pooled, float* __restrict__ cnt) {
  const int wid  = (blockIdx.x * blockDim.x + threadIdx.x) >> 6;
  const int lane = threadIdx.x & 63;
  const int nw   = (gridDim.x * blockDim.x) >> 6;
  const int per  = (N + nw - 1) / nw;
  const int beg  = wid * per;
  if (beg >= N) return;
  const int end = min(beg + per, N);
  int g = batch[beg];
  float acc = 0.f, c = 0.f;
  for (int d = beg; d < end; d++) {
    const int gd = batch[d];
    if (gd != g) {
      atomicAdd(&pooled[g * C2 + lane], acc);
      if (lane == 0) atomicAdd(&cnt[g], c);
      acc = 0.f; c = 0.f; g = gd;
    }
    acc += h[(size_t)d * C2 + lane];
    c += 1.f;
  }
  atomicAdd(&pooled[g * C2 + lane], acc);
  if (lane == 0) atomicAdd(&cnt[g], c);
}

__global__ void final_kernel(const float* __restrict__ pooled, const float* __restrict__ cnt,
                             const float* __restrict__ Wo, const float* __restrict__ bo,
                             float* __restrict__ out) {
  const int lane = threadIdx.x;  // 64 threads
  for (int g = 0; g < NGRAPH; g++) {
    float p = (pooled[g * C2 + lane] / fmaxf(cnt[g], 1.f)) * Wo[lane];
    p += __shfl_xor(p, 1);
    p += __shfl_xor(p, 2);
    p += __shfl_xor(p, 4);
    p += __shfl_xor(p, 8);
    p += __shfl_xor(p, 16);
    p += __shfl_xor(p, 32);
    if (lane == 0) out[g] = p + bo[0];
  }
}

// ---------------------------------------------------------------------------
extern "C" void kernel_launch(void* const* d_in, const int* in_sizes, int n_in,
                              void* d_out, int out_size, void* d_ws, size_t ws_size,
                              hipStream_t stream) {
  const float* x    = (const float*)d_in[0];
  const int*   edge = (const int*)d_in[1];
  const int*   batch= (const int*)d_in[2];
  const float* Wl1  = (const float*)d_in[3];
  const float* Wr1  = (const float*)d_in[4];
  const float* att1 = (const float*)d_in[5];
  const float* b1   = (const float*)d_in[6];
  const float* Wl2  = (const float*)d_in[7];
  const float* Wr2  = (const float*)d_in[8];
  const float* att2 = (const float*)d_in[9];
  const float* b2   = (const float*)d_in[10];
  const float* Wo   = (const float*)d_in[11];
  const float* bo   = (const float*)d_in[12];
  float* out = (float*)d_out;

  char* p = (char*)d_ws;
  unsigned short* xlr1 = (unsigned short*)(p);               // 50000*512*2 = 51,200,000
  unsigned short* h1   = (unsigned short*)(p + 51200000);    // 50000*256*2 = 25,600,000
  unsigned short* xlr2 = (unsigned short*)(p + 76800000);    // 50000*128*2 = 12,800,000
  float*          out2 = (float*)(p + 89600000);             // 50000*64*4  = 12,800,000
  unsigned short* Bt1  = (unsigned short*)(p + 102400000);   // 512*128*2   = 131,072
  unsigned short* Bt2  = (unsigned short*)(p + 102531072);   // 128*256*2   = 65,536
  char* aux = p + 102596608;
  int* deg    = (int*)aux;                                   // 200,000
  int* offs   = (int*)(aux + 200000);                        // 200,064
  int* cursor = (int*)(aux + 400064);                        // 200,000
  int* esrc   = (int*)(aux + 600064);                        // 3,200,000
  float* pooled = (float*)(aux + 3800064);                   // 2,048
  float* cnt    = pooled + NGRAPH * C2;

  const int* edst = edge + E_EDGES;

  hipMemsetAsync(deg, 0, (size_t)N_NODES * 4, stream);
  hipMemsetAsync(pooled, 0, (NGRAPH * C2 + NGRAPH) * 4, stream);

  // weight transpose+cast: Bt1 [512][128], Bt2 [128][256]
  transpose_cat<<<(512 * 128 + 255) / 256, 256, 0, stream>>>(Wl1, Wr1, HC1, 7, Bt1, 512 * 128);
  transpose_cat<<<(128 * 256 + 255) / 256, 256, 0, stream>>>(Wl2, Wr2, C2, 8, Bt2, 128 * 256);

  // CSR by dst
  count_deg<<<(E_EDGES + 255) / 256, 256, 0, stream>>>(edst, E_EDGES, deg);
  scan_kernel<<<1, 1024, 0, stream>>>(deg, offs, cursor, N_NODES);
  scatter_kernel<<<(E_EDGES + 255) / 256, 256, 0, stream>>>(edge, edst, E_EDGES, cursor, esrc);

  // layer 1: [xl1|xr1] = x @ [Wl1|Wr1]  (bf16 out)
  gemm_mfma<FIN, 0><<<dim3((N_NODES + 127) / 128, 4), 256, 0, stream>>>(x, Bt1, xlr1, N_NODES, 512);
  agg1_kernel<<<(N_NODES + 3) / 4, 256, 0, stream>>>(xlr1, att1, b1, offs, esrc, h1, N_NODES);

  // layer 2: [xl2|xr2] = h1 @ [Wl2|Wr2]  (bf16 out)
  gemm_mfma<HC1, 1><<<dim3((N_NODES + 127) / 128, 1), 256, 0, stream>>>(h1, Bt2, xlr2, N_NODES, 128);
  agg2_kernel<<<(N_NODES + 3) / 4, 256, 0, stream>>>(xlr2, att2, b2, offs, esrc, out2, N_NODES);

  // mean pool per graph, then @ Wo + bo
  pool_kernel<<<196, 256, 0, stream>>>(out2, batch, N_NODES, pooled, cnt);
  final_kernel<<<1, 64, 0, stream>>>(pooled, cnt, Wo, bo, out);
}

// Round 4
// 390.463 us; speedup vs baseline: 1.8950x; 1.4645x over previous
//
#include <hip/hip_runtime.h>
#include <math.h>

#define N_NODES 50000
#define E_EDGES 800000
#define FIN     128
#define HC1     256   // H*C = 4*64
#define C2      64
#define NGRAPH  8
#define LOG2E   1.4426950408889634f

typedef short  s16x8 __attribute__((ext_vector_type(8)));
typedef float  f32x4 __attribute__((ext_vector_type(4)));
typedef _Float16 h2  __attribute__((ext_vector_type(2)));

__device__ __forceinline__ unsigned short f2bf(float f) {
  union { float f; unsigned u; } v; v.f = f;
  unsigned r = v.u + 0x7FFFu + ((v.u >> 16) & 1u);  // RNE
  return (unsigned short)(r >> 16);
}
__device__ __forceinline__ h2 bch2(unsigned u) { return __builtin_bit_cast(h2, u); }
__device__ __forceinline__ unsigned short f2h(float f) {
  _Float16 h = (_Float16)f;
  return __builtin_bit_cast(unsigned short, h);
}
__device__ __forceinline__ float h2f(unsigned short u) {
  return (float)__builtin_bit_cast(_Float16, u);
}

__device__ __forceinline__ float fdot2f(h2 a, h2 b, float c) {
#if __has_builtin(__builtin_amdgcn_fdot2)
  return __builtin_amdgcn_fdot2(a, b, c, false);
#else
  return c + (float)a[0] * (float)b[0] + (float)a[1] * (float)b[1];
#endif
}

// leaky_relu in packed f16: max(e, 0.2*e) is exact for both signs.
__device__ __forceinline__ h2 leaky2(h2 e) {
  const h2 c02 = {(_Float16)0.2f, (_Float16)0.2f};
  return __builtin_elementwise_max(e, e * c02);
}

// ----------------------------------------------------- weight transpose+cast
// Bt[n][k] (bf16) from cat(B0,B1), B0/B1 [K][M1] f32. K = 1<<kshift.
__global__ void transpose_cat(const float* __restrict__ B0, const float* __restrict__ B1,
                              int M1, int kshift, unsigned short* __restrict__ Bt, int total) {
  const int idx = blockIdx.x * 256 + threadIdx.x;
  if (idx >= total) return;
  const int K = 1 << kshift;
  const int n = idx >> kshift, k = idx & (K - 1);
  const float* B = (n < M1) ? B0 : B1;
  const int nn = (n < M1) ? n : n - M1;
  Bt[idx] = f2bf(B[(size_t)k * M1 + nn]);
}

// --------------------------------------------------------- MFMA bf16 GEMM
// C[N x Mtot] (f16) = A[N x KTOT] @ Bt^T, Bt [Mtot][KTOT] bf16 pre-transposed.
// 256 thr = 4 waves, tile 128x128, K-chunk 64, wave does 64x64.
// AMODE: 0 = A is f32, 1 = A is f16 (converted to bf16 in staging).
template<int KTOT, int AMODE>
__global__ __launch_bounds__(256) void gemm_mfma(
    const void* __restrict__ Av, const unsigned short* __restrict__ Bt,
    unsigned short* __restrict__ Cc, int N, int Mtot) {
  __shared__ short Asm[128 * 72];
  __shared__ short Bsm[128 * 72];
  const int tid  = threadIdx.x;
  const int lane = tid & 63;
  const int wave = tid >> 6;
  const int lm   = lane & 15, quad = lane >> 4;
  const int r0   = blockIdx.x * 128;
  const int c0   = blockIdx.y * 128;
  const int wrow = (wave & 1) * 64;
  const int wcol = (wave >> 1) * 64;
  const int srow = tid >> 1;
  const int scol = (tid & 1) * 32;

  f32x4 acc[4][4];
#pragma unroll
  for (int mt = 0; mt < 4; mt++)
#pragma unroll
    for (int nt = 0; nt < 4; nt++)
      acc[mt][nt] = (f32x4){0.f, 0.f, 0.f, 0.f};

  const int arow = min(r0 + srow, N - 1);
  for (int kc = 0; kc < KTOT; kc += 64) {
    if (AMODE == 1) {
      const unsigned short* A = (const unsigned short*)Av;
#pragma unroll
      for (int i = 0; i < 4; i++) {
        const int col = scol + i * 8;
        ushort4 u0 = *(const ushort4*)&A[(size_t)arow * KTOT + kc + col];
        ushort4 u1 = *(const ushort4*)&A[(size_t)arow * KTOT + kc + col + 4];
        ushort4 o0, o1;
        o0.x = f2bf(h2f(u0.x)); o0.y = f2bf(h2f(u0.y));
        o0.z = f2bf(h2f(u0.z)); o0.w = f2bf(h2f(u0.w));
        o1.x = f2bf(h2f(u1.x)); o1.y = f2bf(h2f(u1.y));
        o1.z = f2bf(h2f(u1.z)); o1.w = f2bf(h2f(u1.w));
        *(ushort4*)&Asm[srow * 72 + col]     = o0;
        *(ushort4*)&Asm[srow * 72 + col + 4] = o1;
      }
    } else {
      const float* A = (const float*)Av;
#pragma unroll
      for (int i = 0; i < 4; i++) {
        const int col = scol + i * 8;
        const float4 v0 = *(const float4*)&A[(size_t)arow * KTOT + kc + col];
        const float4 v1 = *(const float4*)&A[(size_t)arow * KTOT + kc + col + 4];
        ushort4 u0 = { f2bf(v0.x), f2bf(v0.y), f2bf(v0.z), f2bf(v0.w) };
        ushort4 u1 = { f2bf(v1.x), f2bf(v1.y), f2bf(v1.z), f2bf(v1.w) };
        *(ushort4*)&Asm[srow * 72 + col]     = u0;
        *(ushort4*)&Asm[srow * 72 + col + 4] = u1;
      }
    }
#pragma unroll
    for (int i = 0; i < 4; i++) {
      const int col = scol + i * 8;
      *(uint4*)&Bsm[srow * 72 + col] = *(const uint4*)&Bt[(size_t)(c0 + srow) * KTOT + kc + col];
    }
    __syncthreads();
#pragma unroll
    for (int s = 0; s < 2; s++) {
      s16x8 af[4], bfr[4];
#pragma unroll
      for (int mt = 0; mt < 4; mt++)
        af[mt] = *(const s16x8*)&Asm[(wrow + mt * 16 + lm) * 72 + s * 32 + quad * 8];
#pragma unroll
      for (int nt = 0; nt < 4; nt++)
        bfr[nt] = *(const s16x8*)&Bsm[(wcol + nt * 16 + lm) * 72 + s * 32 + quad * 8];
#pragma unroll
      for (int mt = 0; mt < 4; mt++)
#pragma unroll
        for (int nt = 0; nt < 4; nt++)
          acc[mt][nt] = __builtin_amdgcn_mfma_f32_16x16x32_bf16(af[mt], bfr[nt], acc[mt][nt], 0, 0, 0);
    }
    __syncthreads();
  }
#pragma unroll
  for (int mt = 0; mt < 4; mt++) {
#pragma unroll
    for (int r = 0; r < 4; r++) {
      const int row = r0 + wrow + mt * 16 + quad * 4 + r;
      if (row < N) {
#pragma unroll
        for (int nt = 0; nt < 4; nt++) {
          const int col = c0 + wcol + nt * 16 + lm;
          Cc[(size_t)row * Mtot + col] = f2h(acc[mt][nt][r]);
        }
      }
    }
  }
}

// ------------------------------------------------------------- CSR building
__global__ void count_deg(const int* __restrict__ dst, int E, int* __restrict__ deg) {
  const int e = blockIdx.x * 256 + threadIdx.x;
  if (e < E) atomicAdd(&deg[dst[e]], 1);
}

__global__ __launch_bounds__(1024) void scan1(const int* __restrict__ deg, int N,
                                              int* __restrict__ incl, int* __restrict__ bsum) {
  __shared__ int sd[1024];
  const int tid = threadIdx.x;
  const int i = blockIdx.x * 1024 + tid;
  sd[tid] = (i < N) ? deg[i] : 0;
  __syncthreads();
  for (int off = 1; off < 1024; off <<= 1) {
    int t = 0;
    if (tid >= off) t = sd[tid - off];
    __syncthreads();
    if (tid >= off) sd[tid] += t;
    __syncthreads();
  }
  incl[i] = sd[tid];
  if (tid == 1023) bsum[blockIdx.x] = sd[1023];
}

__global__ void scan2(int* __restrict__ bsum, int nb) {  // exclusive in-place
  int acc = 0;
  for (int b = 0; b < nb; b++) { int t = bsum[b]; bsum[b] = acc; acc += t; }
}

__global__ void scan3(const int* __restrict__ deg, const int* __restrict__ incl,
                      const int* __restrict__ bsum, int N,
                      int* __restrict__ offs, int* __restrict__ cursor) {
  const int i = blockIdx.x * 256 + threadIdx.x;
  if (i >= N) return;
  const int val = incl[i] + bsum[i >> 10];
  offs[i + 1] = val;
  cursor[i] = val - deg[i];
  if (i == 0) offs[0] = 0;
}

__global__ void scatter_kernel(const int* __restrict__ src, const int* __restrict__ dst,
                               int E, int* __restrict__ cursor, int* __restrict__ esrc) {
  const int e = blockIdx.x * 256 + threadIdx.x;
  if (e < E) {
    const int pos = atomicAdd(&cursor[dst[e]], 1);
    esrc[pos] = src[e];
  }
}

// --------------------------------------------- fused gather+softmax+aggregate
// Layer 1: xlr[n][512] f16 (0:256 xl, 256:512 xr). Wave per dst node; lane
// owns 4 ch. Self-loop hoisted; 2-edge unroll w/ dual accumulator chains.
__global__ __launch_bounds__(256) void agg1_kernel(
    const unsigned short* __restrict__ xlr, const float* __restrict__ att,
    const float* __restrict__ bias, const int* __restrict__ offs,
    const int* __restrict__ esrc, unsigned short* __restrict__ out, int N) {
  const int lane = threadIdx.x & 63;
  const int d = blockIdx.x * 4 + (threadIdx.x >> 6);
  if (d >= N) return;
  const uint2 xru = *(const uint2*)(xlr + (size_t)d * 512 + 256 + lane * 4);
  const h2 xr01 = bch2(xru.x), xr23 = bch2(xru.y);
  const float4 at4 = *(const float4*)(att + lane * 4);  // att[h][c], h=lane>>4
  const h2 a01 = {(_Float16)(at4.x * LOG2E), (_Float16)(at4.y * LOG2E)};
  const h2 a23 = {(_Float16)(at4.z * LOG2E), (_Float16)(at4.w * LOG2E)};
  const int beg = offs[d], end = offs[d + 1];

  float l0 = 0.f, ax0 = 0.f, ay0 = 0.f, az0 = 0.f, aw0 = 0.f;
  float l1 = 0.f, ax1 = 0.f, ay1 = 0.f, az1 = 0.f, aw1 = 0.f;

#define EDGE1(s, l, ax, ay, az, aw)                                          \
  {                                                                          \
    const uint2 xu = *(const uint2*)(xlr + (size_t)(s) * 512 + lane * 4);    \
    const h2 x01 = bch2(xu.x), x23 = bch2(xu.y);                             \
    float p = fdot2f(leaky2(x01 + xr01), a01,                                \
                     fdot2f(leaky2(x23 + xr23), a23, 0.f));                  \
    p += __shfl_xor(p, 1);                                                   \
    p += __shfl_xor(p, 2);                                                   \
    p += __shfl_xor(p, 4);                                                   \
    p += __shfl_xor(p, 8);                                                   \
    const float w = exp2f(p);                                                \
    l += w;                                                                  \
    ax = fmaf(w, (float)x01[0], ax);                                         \
    ay = fmaf(w, (float)x01[1], ay);                                         \
    az = fmaf(w, (float)x23[0], az);                                         \
    aw = fmaf(w, (float)x23[1], aw);                                         \
  }

  EDGE1(d, l0, ax0, ay0, az0, aw0)  // self loop
  int i = beg;
  for (; i + 1 < end; i += 2) {
    const int s0 = esrc[i], s1 = esrc[i + 1];
    EDGE1(s0, l0, ax0, ay0, az0, aw0)
    EDGE1(s1, l1, ax1, ay1, az1, aw1)
  }
  if (i < end) { const int s0 = esrc[i]; EDGE1(s0, l1, ax1, ay1, az1, aw1) }
#undef EDGE1

  const float inv = 1.f / (l0 + l1 + 1e-16f);
  const float4 b4 = *(const float4*)(bias + lane * 4);
  ushort4 o;
  o.x = f2h(fmaxf((ax0 + ax1) * inv + b4.x, 0.f));
  o.y = f2h(fmaxf((ay0 + ay1) * inv + b4.y, 0.f));
  o.z = f2h(fmaxf((az0 + az1) * inv + b4.z, 0.f));
  o.w = f2h(fmaxf((aw0 + aw1) * inv + b4.w, 0.f));
  *(ushort4*)(out + (size_t)d * 256 + lane * 4) = o;
}

// Layer 2: xlr[n][128] f16 (0:64 xl, 64:128 xr). Two nodes per wave, 32
// lanes each, lane owns 2 ch (one 4B load). Dual-chain unroll.
__global__ __launch_bounds__(256) void agg2_kernel(
    const unsigned short* __restrict__ xlr, const float* __restrict__ att,
    const float* __restrict__ bias, const int* __restrict__ offs,
    const int* __restrict__ esrc, float* __restrict__ out, int N) {
  const int lane = threadIdx.x & 63;
  const int ln   = lane & 31;
  const int half = lane >> 5;
  const int w    = blockIdx.x * 4 + (threadIdx.x >> 6);
  const int d    = w * 2 + half;
  if (d >= N) return;
  const h2 xr = bch2(*(const unsigned*)(xlr + (size_t)d * 128 + 64 + ln * 2));
  const h2 ah = {(_Float16)(att[ln * 2] * LOG2E), (_Float16)(att[ln * 2 + 1] * LOG2E)};
  const int beg = offs[d], end = offs[d + 1];
  const int len = end - beg;
  const int ml  = max(len, __shfl_xor(len, 32));

  float l0 = 0.f, p00 = 0.f, p01 = 0.f;
  float l1 = 0.f, p10 = 0.f, p11 = 0.f;

#define EDGE2(s, act, l, pa, pb)                                             \
  {                                                                          \
    const h2 x = bch2(*(const unsigned*)(xlr + (size_t)(s) * 128 + ln * 2)); \
    float p = fdot2f(leaky2(x + xr), ah, 0.f);                               \
    p += __shfl_xor(p, 1);                                                   \
    p += __shfl_xor(p, 2);                                                   \
    p += __shfl_xor(p, 4);                                                   \
    p += __shfl_xor(p, 8);                                                   \
    p += __shfl_xor(p, 16);                                                  \
    float wv = exp2f(p);                                                     \
    wv = (act) ? wv : 0.f;                                                   \
    l += wv;                                                                 \
    pa = fmaf(wv, (float)x[0], pa);                                          \
    pb = fmaf(wv, (float)x[1], pb);                                          \
  }

  EDGE2(d, true, l0, p00, p01)  // self loop
  int i = 0;
  for (; i + 1 < ml; i += 2) {
    const bool a0 = i < len, a1 = i + 1 < len;
    const int s0 = a0 ? esrc[min(beg + i, E_EDGES - 1)] : d;
    const int s1 = a1 ? esrc[min(beg + i + 1, E_EDGES - 1)] : d;
    EDGE2(s0, a0, l0, p00, p01)
    EDGE2(s1, a1, l1, p10, p11)
  }
  if (i < ml) {
    const bool a0 = i < len;
    const int s0 = a0 ? esrc[min(beg + i, E_EDGES - 1)] : d;
    EDGE2(s0, a0, l1, p10, p11)
  }
#undef EDGE2

  const float inv = 1.f / (l0 + l1 + 1e-16f);
  float2 o;
  o.x = (p00 + p10) * inv + bias[ln * 2];
  o.y = (p01 + p11) * inv + bias[ln * 2 + 1];
  *(float2*)(out + (size_t)d * 64 + ln * 2) = o;
}

// ------------------------------------------------------------------- pooling
__global__ __launch_bounds__(256) void pool_kernel(
    const float* __restrict__ h, const int* __restrict__ batch, int N,
    float* __restrict__ pooled, float* __restrict__ cnt) {
  const int wid  = (blockIdx.x * blockDim.x + threadIdx.x) >> 6;
  const int lane = threadIdx.x & 63;
  const int nw   = (gridDim.x * blockDim.x) >> 6;
  const int per  = (N + nw - 1) / nw;
  const int beg  = wid * per;
  if (beg >= N) return;
  const int end = min(beg + per, N);
  int g = batch[beg];
  float acc = 0.f, c = 0.f;
  for (int d = beg; d < end; d++) {
    const int gd = batch[d];
    if (gd != g) {
      atomicAdd(&pooled[g * C2 + lane], acc);
      if (lane == 0) atomicAdd(&cnt[g], c);
      acc = 0.f; c = 0.f; g = gd;
    }
    acc += h[(size_t)d * C2 + lane];
    c += 1.f;
  }
  atomicAdd(&pooled[g * C2 + lane], acc);
  if (lane == 0) atomicAdd(&cnt[g], c);
}

__global__ void final_kernel(const float* __restrict__ pooled, const float* __restrict__ cnt,
                             const float* __restrict__ Wo, const float* __restrict__ bo,
                             float* __restrict__ out) {
  const int lane = threadIdx.x;  // 64 threads
  for (int g = 0; g < NGRAPH; g++) {
    float p = (pooled[g * C2 + lane] / fmaxf(cnt[g], 1.f)) * Wo[lane];
    p += __shfl_xor(p, 1);
    p += __shfl_xor(p, 2);
    p += __shfl_xor(p, 4);
    p += __shfl_xor(p, 8);
    p += __shfl_xor(p, 16);
    p += __shfl_xor(p, 32);
    if (lane == 0) out[g] = p + bo[0];
  }
}

// ---------------------------------------------------------------------------
extern "C" void kernel_launch(void* const* d_in, const int* in_sizes, int n_in,
                              void* d_out, int out_size, void* d_ws, size_t ws_size,
                              hipStream_t stream) {
  const float* x    = (const float*)d_in[0];
  const int*   edge = (const int*)d_in[1];
  const int*   batch= (const int*)d_in[2];
  const float* Wl1  = (const float*)d_in[3];
  const float* Wr1  = (const float*)d_in[4];
  const float* att1 = (const float*)d_in[5];
  const float* b1   = (const float*)d_in[6];
  const float* Wl2  = (const float*)d_in[7];
  const float* Wr2  = (const float*)d_in[8];
  const float* att2 = (const float*)d_in[9];
  const float* b2   = (const float*)d_in[10];
  const float* Wo   = (const float*)d_in[11];
  const float* bo   = (const float*)d_in[12];
  float* out = (float*)d_out;

  char* p = (char*)d_ws;
  unsigned short* xlr1 = (unsigned short*)(p);               // 51,200,000
  unsigned short* h1   = (unsigned short*)(p + 51200000);    // 25,600,000
  unsigned short* xlr2 = (unsigned short*)(p + 76800000);    // 12,800,000
  float*          out2 = (float*)(p + 89600000);             // 12,800,000
  unsigned short* Bt1  = (unsigned short*)(p + 102400000);   // 131,072
  unsigned short* Bt2  = (unsigned short*)(p + 102531072);   // 65,536
  char* aux = p + 102596608;
  int* deg    = (int*)aux;                                   // 200,000
  int* offs   = (int*)(aux + 200000);                        // 200,064
  int* cursor = (int*)(aux + 400064);                        // 200,000
  int* esrc   = (int*)(aux + 600064);                        // 3,200,000
  int* incl   = (int*)(aux + 3800064);                       // 200,704
  int* bsum   = (int*)(aux + 4000768);                       // 256
  float* pooled = (float*)(aux + 4001024);                   // 2,048+32
  float* cnt    = pooled + NGRAPH * C2;

  const int* edst = edge + E_EDGES;

  hipMemsetAsync(deg, 0, (size_t)N_NODES * 4, stream);
  hipMemsetAsync(pooled, 0, (NGRAPH * C2 + NGRAPH) * 4, stream);

  transpose_cat<<<(512 * 128 + 255) / 256, 256, 0, stream>>>(Wl1, Wr1, HC1, 7, Bt1, 512 * 128);
  transpose_cat<<<(128 * 256 + 255) / 256, 256, 0, stream>>>(Wl2, Wr2, C2, 8, Bt2, 128 * 256);

  // CSR by dst
  count_deg<<<(E_EDGES + 255) / 256, 256, 0, stream>>>(edst, E_EDGES, deg);
  const int nb = (N_NODES + 1023) / 1024;  // 49
  scan1<<<nb, 1024, 0, stream>>>(deg, N_NODES, incl, bsum);
  scan2<<<1, 1, 0, stream>>>(bsum, nb);
  scan3<<<(N_NODES + 255) / 256, 256, 0, stream>>>(deg, incl, bsum, N_NODES, offs, cursor);
  scatter_kernel<<<(E_EDGES + 255) / 256, 256, 0, stream>>>(edge, edst, E_EDGES, cursor, esrc);

  // layer 1: [xl1|xr1] = x @ [Wl1|Wr1]  (f16 out)
  gemm_mfma<FIN, 0><<<dim3((N_NODES + 127) / 128, 4), 256, 0, stream>>>(x, Bt1, xlr1, N_NODES, 512);
  agg1_kernel<<<(N_NODES + 3) / 4, 256, 0, stream>>>(xlr1, att1, b1, offs, esrc, h1, N_NODES);

  // layer 2: [xl2|xr2] = h1 @ [Wl2|Wr2]  (f16 out)
  gemm_mfma<HC1, 1><<<dim3((N_NODES + 127) / 128, 1), 256, 0, stream>>>(h1, Bt2, xlr2, N_NODES, 128);
  agg2_kernel<<<(N_NODES + 7) / 8, 256, 0, stream>>>(xlr2, att2, b2, offs, esrc, out2, N_NODES);

  pool_kernel<<<196, 256, 0, stream>>>(out2, batch, N_NODES, pooled, cnt);
  final_kernel<<<1, 64, 0, stream>>>(pooled, cnt, Wo, bo, out);
}

// Round 5
// 350.596 us; speedup vs baseline: 2.1105x; 1.1137x over previous
//
#include <hip/hip_runtime.h>
#include <math.h>

#define N_NODES 50000
#define E_EDGES 800000
#define FIN     128
#define HC1     256   // H*C = 4*64
#define C2      64
#define NGRAPH  8
#define LOG2E   1.4426950408889634f

typedef short  s16x8 __attribute__((ext_vector_type(8)));
typedef float  f32x4 __attribute__((ext_vector_type(4)));
typedef _Float16 h2  __attribute__((ext_vector_type(2)));

__device__ __forceinline__ unsigned short f2bf(float f) {
  union { float f; unsigned u; } v; v.f = f;
  unsigned r = v.u + 0x7FFFu + ((v.u >> 16) & 1u);  // RNE
  return (unsigned short)(r >> 16);
}
__device__ __forceinline__ h2 bch2(unsigned u) { return __builtin_bit_cast(h2, u); }
__device__ __forceinline__ unsigned short f2h(float f) {
  _Float16 h = (_Float16)f;
  return __builtin_bit_cast(unsigned short, h);
}
__device__ __forceinline__ float h2f(unsigned short u) {
  return (float)__builtin_bit_cast(_Float16, u);
}

__device__ __forceinline__ float fdot2f(h2 a, h2 b, float c) {
#if __has_builtin(__builtin_amdgcn_fdot2)
  return __builtin_amdgcn_fdot2(a, b, c, false);
#else
  return c + (float)a[0] * (float)b[0] + (float)a[1] * (float)b[1];
#endif
}

// leaky_relu in packed f16: max(e, 0.2*e) exact for both signs.
__device__ __forceinline__ h2 leaky2(h2 e) {
  const h2 c02 = {(_Float16)0.2f, (_Float16)0.2f};
  return __builtin_elementwise_max(e, e * c02);
}

// ----------------------------------------------------- weight transpose+cast
__global__ void transpose_cat(const float* __restrict__ B0, const float* __restrict__ B1,
                              int M1, int kshift, unsigned short* __restrict__ Bt, int total) {
  const int idx = blockIdx.x * 256 + threadIdx.x;
  if (idx >= total) return;
  const int K = 1 << kshift;
  const int n = idx >> kshift, k = idx & (K - 1);
  const float* B = (n < M1) ? B0 : B1;
  const int nn = (n < M1) ? n : n - M1;
  Bt[idx] = f2bf(B[(size_t)k * M1 + nn]);
}

// ------------------------------------------------- GEMM1: x[N,128] -> [N,512]
// Stages full-K A once in LDS; loops 4 column tiles (saves 3x A refetch).
__global__ __launch_bounds__(256) void gemm1_kernel(
    const float* __restrict__ A, const unsigned short* __restrict__ Bt,
    unsigned short* __restrict__ Cc, int N) {
  __shared__ short Asm[128 * 136];   // [row][k] full K=128, pitch 136
  __shared__ short Bsm[128 * 72];    // [col][k] 64-k chunk, pitch 72
  const int tid = threadIdx.x, lane = tid & 63, wave = tid >> 6;
  const int lm = lane & 15, quad = lane >> 4;
  const int r0 = blockIdx.x * 128;
  const int wrow = (wave & 1) * 64, wcol = (wave >> 1) * 64;
  const int srow = tid >> 1;
  const int scolA = (tid & 1) * 64;
  const int scolB = (tid & 1) * 32;
  const int arow = min(r0 + srow, N - 1);
#pragma unroll
  for (int i = 0; i < 8; i++) {
    const int col = scolA + i * 8;
    const float4 v0 = *(const float4*)&A[(size_t)arow * 128 + col];
    const float4 v1 = *(const float4*)&A[(size_t)arow * 128 + col + 4];
    ushort4 u0 = { f2bf(v0.x), f2bf(v0.y), f2bf(v0.z), f2bf(v0.w) };
    ushort4 u1 = { f2bf(v1.x), f2bf(v1.y), f2bf(v1.z), f2bf(v1.w) };
    *(ushort4*)&Asm[srow * 136 + col]     = u0;
    *(ushort4*)&Asm[srow * 136 + col + 4] = u1;
  }
  for (int ct = 0; ct < 4; ct++) {
    f32x4 acc[4][4];
#pragma unroll
    for (int mt = 0; mt < 4; mt++)
#pragma unroll
      for (int nt = 0; nt < 4; nt++)
        acc[mt][nt] = (f32x4){0.f, 0.f, 0.f, 0.f};
    for (int kc = 0; kc < 128; kc += 64) {
      __syncthreads();  // A staged (first pass) / Bsm free for overwrite
#pragma unroll
      for (int i = 0; i < 4; i++) {
        const int col = scolB + i * 8;
        *(uint4*)&Bsm[srow * 72 + col] =
            *(const uint4*)&Bt[(size_t)(ct * 128 + srow) * 128 + kc + col];
      }
      __syncthreads();
#pragma unroll
      for (int s = 0; s < 2; s++) {
        s16x8 af[4], bfr[4];
#pragma unroll
        for (int mt = 0; mt < 4; mt++)
          af[mt] = *(const s16x8*)&Asm[(wrow + mt * 16 + lm) * 136 + kc + s * 32 + quad * 8];
#pragma unroll
        for (int nt = 0; nt < 4; nt++)
          bfr[nt] = *(const s16x8*)&Bsm[(wcol + nt * 16 + lm) * 72 + s * 32 + quad * 8];
#pragma unroll
        for (int mt = 0; mt < 4; mt++)
#pragma unroll
          for (int nt = 0; nt < 4; nt++)
            acc[mt][nt] = __builtin_amdgcn_mfma_f32_16x16x32_bf16(af[mt], bfr[nt], acc[mt][nt], 0, 0, 0);
      }
    }
#pragma unroll
    for (int mt = 0; mt < 4; mt++) {
#pragma unroll
      for (int r = 0; r < 4; r++) {
        const int row = r0 + wrow + mt * 16 + quad * 4 + r;
        if (row < N) {
#pragma unroll
          for (int nt = 0; nt < 4; nt++) {
            const int col = ct * 128 + wcol + nt * 16 + lm;
            Cc[(size_t)row * 512 + col] = f2h(acc[mt][nt][r]);
          }
        }
      }
    }
  }
}

// --------------------------------------------------------- GEMM2 (templated)
// C[N x Mtot] f16 = A[N x KTOT] f16 @ Bt^T, Bt [Mtot][KTOT] bf16.
template<int KTOT>
__global__ __launch_bounds__(256) void gemm_mfma(
    const unsigned short* __restrict__ A, const unsigned short* __restrict__ Bt,
    unsigned short* __restrict__ Cc, int N, int Mtot) {
  __shared__ short Asm[128 * 72];
  __shared__ short Bsm[128 * 72];
  const int tid  = threadIdx.x;
  const int lane = tid & 63;
  const int wave = tid >> 6;
  const int lm   = lane & 15, quad = lane >> 4;
  const int r0   = blockIdx.x * 128;
  const int c0   = blockIdx.y * 128;
  const int wrow = (wave & 1) * 64;
  const int wcol = (wave >> 1) * 64;
  const int srow = tid >> 1;
  const int scol = (tid & 1) * 32;

  f32x4 acc[4][4];
#pragma unroll
  for (int mt = 0; mt < 4; mt++)
#pragma unroll
    for (int nt = 0; nt < 4; nt++)
      acc[mt][nt] = (f32x4){0.f, 0.f, 0.f, 0.f};

  const int arow = min(r0 + srow, N - 1);
  for (int kc = 0; kc < KTOT; kc += 64) {
#pragma unroll
    for (int i = 0; i < 4; i++) {
      const int col = scol + i * 8;
      ushort4 u0 = *(const ushort4*)&A[(size_t)arow * KTOT + kc + col];
      ushort4 u1 = *(const ushort4*)&A[(size_t)arow * KTOT + kc + col + 4];
      ushort4 o0, o1;
      o0.x = f2bf(h2f(u0.x)); o0.y = f2bf(h2f(u0.y));
      o0.z = f2bf(h2f(u0.z)); o0.w = f2bf(h2f(u0.w));
      o1.x = f2bf(h2f(u1.x)); o1.y = f2bf(h2f(u1.y));
      o1.z = f2bf(h2f(u1.z)); o1.w = f2bf(h2f(u1.w));
      *(ushort4*)&Asm[srow * 72 + col]     = o0;
      *(ushort4*)&Asm[srow * 72 + col + 4] = o1;
    }
#pragma unroll
    for (int i = 0; i < 4; i++) {
      const int col = scol + i * 8;
      *(uint4*)&Bsm[srow * 72 + col] = *(const uint4*)&Bt[(size_t)(c0 + srow) * KTOT + kc + col];
    }
    __syncthreads();
#pragma unroll
    for (int s = 0; s < 2; s++) {
      s16x8 af[4], bfr[4];
#pragma unroll
      for (int mt = 0; mt < 4; mt++)
        af[mt] = *(const s16x8*)&Asm[(wrow + mt * 16 + lm) * 72 + s * 32 + quad * 8];
#pragma unroll
      for (int nt = 0; nt < 4; nt++)
        bfr[nt] = *(const s16x8*)&Bsm[(wcol + nt * 16 + lm) * 72 + s * 32 + quad * 8];
#pragma unroll
      for (int mt = 0; mt < 4; mt++)
#pragma unroll
        for (int nt = 0; nt < 4; nt++)
          acc[mt][nt] = __builtin_amdgcn_mfma_f32_16x16x32_bf16(af[mt], bfr[nt], acc[mt][nt], 0, 0, 0);
    }
    __syncthreads();
  }
#pragma unroll
  for (int mt = 0; mt < 4; mt++) {
#pragma unroll
    for (int r = 0; r < 4; r++) {
      const int row = r0 + wrow + mt * 16 + quad * 4 + r;
      if (row < N) {
#pragma unroll
        for (int nt = 0; nt < 4; nt++) {
          const int col = c0 + wcol + nt * 16 + lm;
          Cc[(size_t)row * Mtot + col] = f2h(acc[mt][nt][r]);
        }
      }
    }
  }
}

// ------------------------------------------------------------- CSR building
__global__ void count_deg(const int* __restrict__ dst, int E, int* __restrict__ deg) {
  const int e = blockIdx.x * 256 + threadIdx.x;
  if (e < E) atomicAdd(&deg[dst[e]], 1);
}

__global__ __launch_bounds__(1024) void scan1(const int* __restrict__ deg, int N,
                                              int* __restrict__ incl, int* __restrict__ bsum) {
  __shared__ int sd[1024];
  const int tid = threadIdx.x;
  const int i = blockIdx.x * 1024 + tid;
  sd[tid] = (i < N) ? deg[i] : 0;
  __syncthreads();
  for (int off = 1; off < 1024; off <<= 1) {
    int t = 0;
    if (tid >= off) t = sd[tid - off];
    __syncthreads();
    if (tid >= off) sd[tid] += t;
    __syncthreads();
  }
  incl[i] = sd[tid];
  if (tid == 1023) bsum[blockIdx.x] = sd[1023];
}

// single-wave shfl exclusive scan (nb <= 64)
__global__ void scan2(int* __restrict__ bsum, int nb) {
  const int lane = threadIdx.x;
  const int orig = (lane < nb) ? bsum[lane] : 0;
  int v = orig;
  for (int off = 1; off < 64; off <<= 1) {
    int t = __shfl_up(v, off);
    if (lane >= off) v += t;
  }
  if (lane < nb) bsum[lane] = v - orig;  // exclusive
}

__global__ void scan3(const int* __restrict__ deg, const int* __restrict__ incl,
                      const int* __restrict__ bsum, int N,
                      int* __restrict__ offs, int* __restrict__ cursor) {
  const int i = blockIdx.x * 256 + threadIdx.x;
  if (i >= N) return;
  const int val = incl[i] + bsum[i >> 10];
  offs[i + 1] = val;
  cursor[i] = val - deg[i];
  if (i == 0) offs[0] = 0;
}

__global__ void scatter_kernel(const int* __restrict__ src, const int* __restrict__ dst,
                               int E, int* __restrict__ cursor, int* __restrict__ esrc) {
  const int e = blockIdx.x * 256 + threadIdx.x;
  if (e < E) {
    const int pos = atomicAdd(&cursor[dst[e]], 1);
    esrc[pos] = src[e];
  }
}

// --------------------------------------------- fused gather+softmax+aggregate
// Layer 1: xlr[n][512] f16 (0:256 xl, 256:512 xr). Wave per dst; 32 lanes per
// edge (lane owns 8 ch = 16B gather), halves process even/odd edges, 2-chain
// unroll per half (4 edges in flight). 3 shuffles/edge.
__global__ __launch_bounds__(256) void agg1_kernel(
    const unsigned short* __restrict__ xlr, const float* __restrict__ att,
    const float* __restrict__ bias, const int* __restrict__ offs,
    const int* __restrict__ esrc, unsigned short* __restrict__ out, int N) {
  const int lane = threadIdx.x & 63;
  const int ln = lane & 31, half = lane >> 5;
  const int d = blockIdx.x * 4 + (threadIdx.x >> 6);
  if (d >= N) return;
  const uint4 xru = *(const uint4*)(xlr + (size_t)d * 512 + 256 + ln * 8);
  const h2 xr01 = bch2(xru.x), xr23 = bch2(xru.y), xr45 = bch2(xru.z), xr67 = bch2(xru.w);
  const float4 at0 = *(const float4*)(att + ln * 8);      // att flat [h*64+c]
  const float4 at1 = *(const float4*)(att + ln * 8 + 4);  // head = ln>>3
  const h2 A01 = {(_Float16)(at0.x * LOG2E), (_Float16)(at0.y * LOG2E)};
  const h2 A23 = {(_Float16)(at0.z * LOG2E), (_Float16)(at0.w * LOG2E)};
  const h2 A45 = {(_Float16)(at1.x * LOG2E), (_Float16)(at1.y * LOG2E)};
  const h2 A67 = {(_Float16)(at1.z * LOG2E), (_Float16)(at1.w * LOG2E)};
  const int beg = offs[d], end = offs[d + 1];
  const int len = end - beg;

  float l[2] = {0.f, 0.f};
  float ac[2][8] = {};

#define EDGE1(s, c)                                                           \
  {                                                                           \
    const uint4 xu = *(const uint4*)(xlr + (size_t)(s) * 512 + ln * 8);       \
    const h2 x01 = bch2(xu.x), x23 = bch2(xu.y);                              \
    const h2 x45 = bch2(xu.z), x67 = bch2(xu.w);                              \
    float p = fdot2f(leaky2(x01 + xr01), A01,                                 \
              fdot2f(leaky2(x23 + xr23), A23,                                 \
              fdot2f(leaky2(x45 + xr45), A45,                                 \
              fdot2f(leaky2(x67 + xr67), A67, 0.f))));                        \
    p += __shfl_xor(p, 1);                                                    \
    p += __shfl_xor(p, 2);                                                    \
    p += __shfl_xor(p, 4);                                                    \
    const float w = exp2f(p);                                                 \
    l[c] += w;                                                                \
    ac[c][0] = fmaf(w, (float)x01[0], ac[c][0]);                              \
    ac[c][1] = fmaf(w, (float)x01[1], ac[c][1]);                              \
    ac[c][2] = fmaf(w, (float)x23[0], ac[c][2]);                              \
    ac[c][3] = fmaf(w, (float)x23[1], ac[c][3]);                              \
    ac[c][4] = fmaf(w, (float)x45[0], ac[c][4]);                              \
    ac[c][5] = fmaf(w, (float)x45[1], ac[c][5]);                              \
    ac[c][6] = fmaf(w, (float)x67[0], ac[c][6]);                              \
    ac[c][7] = fmaf(w, (float)x67[1], ac[c][7]);                              \
  }

  if (half == 0) EDGE1(d, 0)  // self loop (shuffles stay in 8-lane groups)
  int j = half;
  for (; j + 2 < len; j += 4) {
    const int s0 = esrc[beg + j], s1 = esrc[beg + j + 2];
    EDGE1(s0, 0)
    EDGE1(s1, 1)
  }
  if (j < len) { const int s0 = esrc[beg + j]; EDGE1(s0, 0) j += 2; }
  if (j < len) { const int s1 = esrc[beg + j]; EDGE1(s1, 1) }
#undef EDGE1

  float lt = l[0] + l[1];
  lt += __shfl_xor(lt, 32);
  const float inv = 1.f / (lt + 1e-16f);
  float o[8];
#pragma unroll
  for (int t = 0; t < 8; t++) {
    o[t] = ac[0][t] + ac[1][t];
    o[t] += __shfl_xor(o[t], 32);
  }
  if (half == 0) {
    const float4 b0 = *(const float4*)(bias + ln * 8);
    const float4 b1v = *(const float4*)(bias + ln * 8 + 4);
    ushort4 u0, u1;
    u0.x = f2h(fmaxf(o[0] * inv + b0.x, 0.f));
    u0.y = f2h(fmaxf(o[1] * inv + b0.y, 0.f));
    u0.z = f2h(fmaxf(o[2] * inv + b0.z, 0.f));
    u0.w = f2h(fmaxf(o[3] * inv + b0.w, 0.f));
    u1.x = f2h(fmaxf(o[4] * inv + b1v.x, 0.f));
    u1.y = f2h(fmaxf(o[5] * inv + b1v.y, 0.f));
    u1.z = f2h(fmaxf(o[6] * inv + b1v.z, 0.f));
    u1.w = f2h(fmaxf(o[7] * inv + b1v.w, 0.f));
    *(ushort4*)(out + (size_t)d * 256 + ln * 8)     = u0;
    *(ushort4*)(out + (size_t)d * 256 + ln * 8 + 4) = u1;
  }
}

// Layer 2: xlr[n][128] f16 (0:64 xl, 64:128 xr). Wave per dst; 16 lanes per
// edge (lane owns 4 ch = 8B gather), quarters process edges j%4==q, 2-chain
// unroll per quarter (8 edges in flight). 4 shuffles/edge.
__global__ __launch_bounds__(256) void agg2_kernel(
    const unsigned short* __restrict__ xlr, const float* __restrict__ att,
    const float* __restrict__ bias, const int* __restrict__ offs,
    const int* __restrict__ esrc, float* __restrict__ out, int N) {
  const int lane = threadIdx.x & 63;
  const int ln = lane & 15, q = lane >> 4;
  const int d = blockIdx.x * 4 + (threadIdx.x >> 6);
  if (d >= N) return;
  const uint2 xru = *(const uint2*)(xlr + (size_t)d * 128 + 64 + ln * 4);
  const h2 xr01 = bch2(xru.x), xr23 = bch2(xru.y);
  const float4 at = *(const float4*)(att + ln * 4);
  const h2 A01 = {(_Float16)(at.x * LOG2E), (_Float16)(at.y * LOG2E)};
  const h2 A23 = {(_Float16)(at.z * LOG2E), (_Float16)(at.w * LOG2E)};
  const int beg = offs[d], end = offs[d + 1];
  const int len = end - beg;

  float l[2] = {0.f, 0.f};
  float ac[2][4] = {};

#define EDGE2(s, c)                                                           \
  {                                                                           \
    const uint2 xu = *(const uint2*)(xlr + (size_t)(s) * 128 + ln * 4);       \
    const h2 x01 = bch2(xu.x), x23 = bch2(xu.y);                              \
    float p = fdot2f(leaky2(x01 + xr01), A01,                                 \
              fdot2f(leaky2(x23 + xr23), A23, 0.f));                          \
    p += __shfl_xor(p, 1);                                                    \
    p += __shfl_xor(p, 2);                                                    \
    p += __shfl_xor(p, 4);                                                    \
    p += __shfl_xor(p, 8);                                                    \
    const float w = exp2f(p);                                                 \
    l[c] += w;                                                                \
    ac[c][0] = fmaf(w, (float)x01[0], ac[c][0]);                              \
    ac[c][1] = fmaf(w, (float)x01[1], ac[c][1]);                              \
    ac[c][2] = fmaf(w, (float)x23[0], ac[c][2]);                              \
    ac[c][3] = fmaf(w, (float)x23[1], ac[c][3]);                              \
  }

  if (q == 0) EDGE2(d, 0)  // self loop (shuffles stay in 16-lane group 0)
  int j = q;
  for (; j + 4 < len; j += 8) {
    const int s0 = esrc[beg + j], s1 = esrc[beg + j + 4];
    EDGE2(s0, 0)
    EDGE2(s1, 1)
  }
  if (j < len) { const int s0 = esrc[beg + j]; EDGE2(s0, 0) j += 4; }
  if (j < len) { const int s1 = esrc[beg + j]; EDGE2(s1, 1) }
#undef EDGE2

  float lt = l[0] + l[1];
  lt += __shfl_xor(lt, 16);
  lt += __shfl_xor(lt, 32);
  const float inv = 1.f / (lt + 1e-16f);
  float o[4];
#pragma unroll
  for (int t = 0; t < 4; t++) {
    o[t] = ac[0][t] + ac[1][t];
    o[t] += __shfl_xor(o[t], 16);
    o[t] += __shfl_xor(o[t], 32);
  }
  if (q == 0) {
    const float4 b4 = *(const float4*)(bias + ln * 4);
    float4 ov;
    ov.x = o[0] * inv + b4.x;
    ov.y = o[1] * inv + b4.y;
    ov.z = o[2] * inv + b4.z;
    ov.w = o[3] * inv + b4.w;
    *(float4*)(out + (size_t)d * 64 + ln * 4) = ov;
  }
}

// ------------------------------------------------------------------- pooling
__global__ __launch_bounds__(256) void pool_kernel(
    const float* __restrict__ h, const int* __restrict__ batch, int N,
    float* __restrict__ pooled, float* __restrict__ cnt) {
  const int wid  = (blockIdx.x * blockDim.x + threadIdx.x) >> 6;
  const int lane = threadIdx.x & 63;
  const int nw   = (gridDim.x * blockDim.x) >> 6;
  const int per  = (N + nw - 1) / nw;
  const int beg  = wid * per;
  if (beg >= N) return;
  const int end = min(beg + per, N);
  int g = batch[beg];
  float acc = 0.f, c = 0.f;
  for (int d = beg; d < end; d++) {
    const int gd = batch[d];
    if (gd != g) {
      atomicAdd(&pooled[g * C2 + lane], acc);
      if (lane == 0) atomicAdd(&cnt[g], c);
      acc = 0.f; c = 0.f; g = gd;
    }
    acc += h[(size_t)d * C2 + lane];
    c += 1.f;
  }
  atomicAdd(&pooled[g * C2 + lane], acc);
  if (lane == 0) atomicAdd(&cnt[g], c);
}

__global__ void final_kernel(const float* __restrict__ pooled, const float* __restrict__ cnt,
                             const float* __restrict__ Wo, const float* __restrict__ bo,
                             float* __restrict__ out) {
  const int lane = threadIdx.x;  // 64 threads
  for (int g = 0; g < NGRAPH; g++) {
    float p = (pooled[g * C2 + lane] / fmaxf(cnt[g], 1.f)) * Wo[lane];
    p += __shfl_xor(p, 1);
    p += __shfl_xor(p, 2);
    p += __shfl_xor(p, 4);
    p += __shfl_xor(p, 8);
    p += __shfl_xor(p, 16);
    p += __shfl_xor(p, 32);
    if (lane == 0) out[g] = p + bo[0];
  }
}

// ---------------------------------------------------------------------------
extern "C" void kernel_launch(void* const* d_in, const int* in_sizes, int n_in,
                              void* d_out, int out_size, void* d_ws, size_t ws_size,
                              hipStream_t stream) {
  const float* x    = (const float*)d_in[0];
  const int*   edge = (const int*)d_in[1];
  const int*   batch= (const int*)d_in[2];
  const float* Wl1  = (const float*)d_in[3];
  const float* Wr1  = (const float*)d_in[4];
  const float* att1 = (const float*)d_in[5];
  const float* b1   = (const float*)d_in[6];
  const float* Wl2  = (const float*)d_in[7];
  const float* Wr2  = (const float*)d_in[8];
  const float* att2 = (const float*)d_in[9];
  const float* b2   = (const float*)d_in[10];
  const float* Wo   = (const float*)d_in[11];
  const float* bo   = (const float*)d_in[12];
  float* out = (float*)d_out;

  char* p = (char*)d_ws;
  unsigned short* xlr1 = (unsigned short*)(p);               // 51,200,000
  unsigned short* h1   = (unsigned short*)(p + 51200000);    // 25,600,000
  unsigned short* xlr2 = (unsigned short*)(p + 76800000);    // 12,800,000
  float*          out2 = (float*)(p + 89600000);             // 12,800,000
  unsigned short* Bt1  = (unsigned short*)(p + 102400000);   // 131,072
  unsigned short* Bt2  = (unsigned short*)(p + 102531072);   // 65,536
  char* aux = p + 102596608;
  int* deg    = (int*)aux;                                   // 200,000
  int* offs   = (int*)(aux + 200000);                        // 200,064
  int* cursor = (int*)(aux + 400064);                        // 200,000
  int* esrc   = (int*)(aux + 600064);                        // 3,200,000
  int* incl   = (int*)(aux + 3800064);                       // 200,704
  int* bsum   = (int*)(aux + 4000768);                       // 256
  float* pooled = (float*)(aux + 4001024);                   // 2,048+32
  float* cnt    = pooled + NGRAPH * C2;

  const int* edst = edge + E_EDGES;

  hipMemsetAsync(deg, 0, (size_t)N_NODES * 4, stream);
  hipMemsetAsync(pooled, 0, (NGRAPH * C2 + NGRAPH) * 4, stream);

  transpose_cat<<<(512 * 128 + 255) / 256, 256, 0, stream>>>(Wl1, Wr1, HC1, 7, Bt1, 512 * 128);
  transpose_cat<<<(128 * 256 + 255) / 256, 256, 0, stream>>>(Wl2, Wr2, C2, 8, Bt2, 128 * 256);

  // CSR by dst
  count_deg<<<(E_EDGES + 255) / 256, 256, 0, stream>>>(edst, E_EDGES, deg);
  const int nb = (N_NODES + 1023) / 1024;  // 49
  scan1<<<nb, 1024, 0, stream>>>(deg, N_NODES, incl, bsum);
  scan2<<<1, 64, 0, stream>>>(bsum, nb);
  scan3<<<(N_NODES + 255) / 256, 256, 0, stream>>>(deg, incl, bsum, N_NODES, offs, cursor);
  scatter_kernel<<<(E_EDGES + 255) / 256, 256, 0, stream>>>(edge, edst, E_EDGES, cursor, esrc);

  // layer 1: [xl1|xr1] = x @ [Wl1|Wr1]  (f16 out)
  gemm1_kernel<<<(N_NODES + 127) / 128, 256, 0, stream>>>(x, Bt1, xlr1, N_NODES);
  agg1_kernel<<<(N_NODES + 3) / 4, 256, 0, stream>>>(xlr1, att1, b1, offs, esrc, h1, N_NODES);

  // layer 2: [xl2|xr2] = h1 @ [Wl2|Wr2]  (f16 out)
  gemm_mfma<HC1><<<dim3((N_NODES + 127) / 128, 1), 256, 0, stream>>>(h1, Bt2, xlr2, N_NODES, 128);
  agg2_kernel<<<(N_NODES + 3) / 4, 256, 0, stream>>>(xlr2, att2, b2, offs, esrc, out2, N_NODES);

  pool_kernel<<<196, 256, 0, stream>>>(out2, batch, N_NODES, pooled, cnt);
  final_kernel<<<1, 64, 0, stream>>>(pooled, cnt, Wo, bo, out);
}